// Round 1
// baseline (1060.539 us; speedup 1.0000x reference)
//
#include <hip/hip_runtime.h>

// GNN_Critic: 2-layer SAGEConv (F: 1 -> 16 -> 1) + global_add_pool.
// Algebraic reduction: layer-2 is linear in h, so only per-node scalars
//   p[n] = h[n,:] . W2l   (aggregated over edges -> s2)
//   q[n] = h[n,:] . W2r
// are needed; the 16-dim hidden vector is never materialized in memory.

// ---------------------------------------------------------------------------
// Edge aggregation: accum[dst] += val[src]; optionally deg[dst] += 1.
// Vectorized int4 index loads (src half then dst half of edge_index).
__global__ void edge_agg_kernel(const int* __restrict__ ei,
                                const float* __restrict__ val,
                                float* __restrict__ accum,
                                float* __restrict__ deg,
                                int E) {
    const int4* src4 = (const int4*)ei;
    const int4* dst4 = (const int4*)(ei + E);
    int E4 = E >> 2;
    int i = blockIdx.x * blockDim.x + threadIdx.x;
    int stride = gridDim.x * blockDim.x;
    for (int e = i; e < E4; e += stride) {
        int4 s = src4[e];
        int4 d = dst4[e];
        atomicAdd(&accum[d.x], val[s.x]);
        atomicAdd(&accum[d.y], val[s.y]);
        atomicAdd(&accum[d.z], val[s.z]);
        atomicAdd(&accum[d.w], val[s.w]);
        if (deg != nullptr) {
            atomicAdd(&deg[d.x], 1.0f);
            atomicAdd(&deg[d.y], 1.0f);
            atomicAdd(&deg[d.z], 1.0f);
            atomicAdd(&deg[d.w], 1.0f);
        }
    }
    // tail (E not divisible by 4)
    int tail_start = E4 << 2;
    int t = tail_start + i;
    if (t < E) {
        int s = ei[t];
        int d = ei[E + t];
        atomicAdd(&accum[d], val[s]);
        if (deg != nullptr) atomicAdd(&deg[d], 1.0f);
    }
}

// ---------------------------------------------------------------------------
// Node pass 1: mean1 = sum1/max(deg,1); h[f] = relu(mean1*W1l[f] + b1[f] + x*W1r[f]);
// p = h.W2l, q = h.W2r.
__global__ void node_pass1_kernel(const float* __restrict__ x,
                                  const float* __restrict__ sum1,
                                  const float* __restrict__ deg,
                                  const float* __restrict__ W1l,
                                  const float* __restrict__ b1,
                                  const float* __restrict__ W1r,
                                  const float* __restrict__ W2l,
                                  const float* __restrict__ W2r,
                                  float* __restrict__ p,
                                  float* __restrict__ q,
                                  int N) {
    __shared__ float s_w1l[16], s_b1[16], s_w1r[16], s_w2l[16], s_w2r[16];
    if (threadIdx.x < 16) {
        s_w1l[threadIdx.x] = W1l[threadIdx.x];
        s_b1[threadIdx.x]  = b1[threadIdx.x];
        s_w1r[threadIdx.x] = W1r[threadIdx.x];
        s_w2l[threadIdx.x] = W2l[threadIdx.x];
        s_w2r[threadIdx.x] = W2r[threadIdx.x];
    }
    __syncthreads();
    int i = blockIdx.x * blockDim.x + threadIdx.x;
    int stride = gridDim.x * blockDim.x;
    for (int n = i; n < N; n += stride) {
        float xv = x[n];
        float m  = sum1[n] / fmaxf(deg[n], 1.0f);
        float pa = 0.0f, qa = 0.0f;
#pragma unroll
        for (int f = 0; f < 16; ++f) {
            float h = fmaf(m, s_w1l[f], fmaf(xv, s_w1r[f], s_b1[f]));
            h = fmaxf(h, 0.0f);
            pa = fmaf(h, s_w2l[f], pa);
            qa = fmaf(h, s_w2r[f], qa);
        }
        p[n] = pa;
        q[n] = qa;
    }
}

// ---------------------------------------------------------------------------
// Node pass 2 + pool: h2 = s2/max(deg,1) + b2 + q; out[batch[n]] += h2.
// batch is sorted -> wave-level segmented reduction before atomics.
__global__ void node_pass2_kernel(const float* __restrict__ s2,
                                  const float* __restrict__ deg,
                                  const float* __restrict__ q,
                                  const float* __restrict__ b2,
                                  const int* __restrict__ batch,
                                  float* __restrict__ out,
                                  int N) {
    int i = blockIdx.x * blockDim.x + threadIdx.x;
    float b2v = b2[0];
    float val = 0.0f;
    int g;
    if (i < N) {
        val = s2[i] / fmaxf(deg[i], 1.0f) + b2v + q[i];
        g = batch[i];
    } else {
        g = batch[N - 1];  // pad lanes contribute 0 to a valid graph id
    }
    // wave = 64 lanes; batch sorted, so most waves are single-graph
    int g0 = __shfl(g, 0);
    unsigned long long same = __ballot(g == g0);
    if (same == ~0ULL) {
        for (int off = 32; off > 0; off >>= 1) val += __shfl_down(val, off);
        if ((threadIdx.x & 63) == 0) atomicAdd(&out[g0], val);
    } else {
        atomicAdd(&out[g], val);
    }
}

// ---------------------------------------------------------------------------
extern "C" void kernel_launch(void* const* d_in, const int* in_sizes, int n_in,
                              void* d_out, int out_size, void* d_ws, size_t ws_size,
                              hipStream_t stream) {
    const float* x     = (const float*)d_in[0];
    const int*   ei    = (const int*)d_in[1];   // [2, E] flat: src then dst
    const int*   batch = (const int*)d_in[2];
    // d_in[3] = batch_size scalar (== out_size), unused
    const float* W1l = (const float*)d_in[4];
    const float* b1  = (const float*)d_in[5];
    const float* W1r = (const float*)d_in[6];
    const float* W2l = (const float*)d_in[7];
    const float* b2  = (const float*)d_in[8];
    const float* W2r = (const float*)d_in[9];

    const int N = in_sizes[0];        // 200000
    const int E = in_sizes[1] / 2;    // 6400000
    float* out = (float*)d_out;       // [512]

    // workspace layout (floats): deg[N] | sum1_or_s2[N] | p[N] | q[N]
    float* deg  = (float*)d_ws;
    float* sum1 = deg + N;   // reused as s2 after node_pass1
    float* p    = sum1 + N;
    float* q    = p + N;

    // zero: out, deg, sum1 (poisoned with 0xAA by harness)
    hipMemsetAsync(d_out, 0, (size_t)out_size * sizeof(float), stream);
    hipMemsetAsync(deg, 0, (size_t)2 * N * sizeof(float), stream);

    const int BS = 256;
    int E4 = E >> 2;
    int edge_blocks = (E4 + BS - 1) / BS;
    int node_blocks = (N + BS - 1) / BS;

    // layer 1 edge aggregation (+ degree)
    edge_agg_kernel<<<edge_blocks, BS, 0, stream>>>(ei, x, sum1, deg, E);
    // layer 1 node compute -> p, q
    node_pass1_kernel<<<node_blocks, BS, 0, stream>>>(x, sum1, deg, W1l, b1, W1r,
                                                      W2l, W2r, p, q, N);
    // re-zero the sum buffer for reuse as s2
    hipMemsetAsync(sum1, 0, (size_t)N * sizeof(float), stream);
    // layer 2 edge aggregation of p
    edge_agg_kernel<<<edge_blocks, BS, 0, stream>>>(ei, p, sum1, nullptr, E);
    // layer 2 node compute + pool
    node_pass2_kernel<<<node_blocks, BS, 0, stream>>>(sum1, deg, q, b2, batch,
                                                      out, N);
}

// Round 2
// 720.886 us; speedup vs baseline: 1.4712x; 1.4712x over previous
//
#include <hip/hip_runtime.h>

// GNN_Critic: 2-layer SAGEConv (F: 1 -> 16 -> 1) + global_add_pool.
// Algebraic reduction: layer-2 is linear in h, so only per-node scalars
//   p[n] = h[n,:] . W2l   (aggregated over edges -> s2)
//   q[n] = h[n,:] . W2r
// are needed; the 16-dim hidden vector is never materialized.
//
// Round-2 structural change: XCC-local atomics. Each XCD accumulates into a
// PRIVATE copy of the per-node accumulator (indexed by HW_REG_XCC_ID), using
// workgroup-scope relaxed atomics that execute in the local L2 (no sc1, no
// trip to the device coherence point). Kernel-boundary L2 writeback makes the
// copies visible to the subsequent reduce pass. Pass 1 additionally packs
// (sum, degree) into ONE u64 atomic: count in bits[63:42], biased fixed-point
// sum (scale 2^20, bias 2^31 per add) in bits[41:0].

#define NUM_XCD 8

__device__ __forceinline__ unsigned get_xcc_id() {
    unsigned x;
    asm volatile("s_getreg_b32 %0, hwreg(HW_REG_XCC_ID)" : "=s"(x));
    return x & (NUM_XCD - 1);
}

__device__ __forceinline__ unsigned long long pack_val(float v) {
    // v ~ N(0,1); |v| << 2^11 so fx is always positive after bias.
    long long fx = (long long)rintf(v * 1048576.0f) + (1LL << 31);
    return (1ULL << 42) + (unsigned long long)fx;
}

// ---------------------------------------------------------------------------
// Edge pass 1: pack8[xcc][dst] += pack(x[src])   (u64, L2-local atomic)
__global__ void edge_pass1_kernel(const int* __restrict__ ei,
                                  const float* __restrict__ x,
                                  unsigned long long* __restrict__ pack8,
                                  int E, int N) {
    unsigned long long* __restrict__ base =
        pack8 + (size_t)get_xcc_id() * (size_t)N;
    const int4* src4 = (const int4*)ei;
    const int4* dst4 = (const int4*)(ei + E);
    int E4 = E >> 2;
    int i = blockIdx.x * blockDim.x + threadIdx.x;
    int stride = gridDim.x * blockDim.x;
    for (int e = i; e < E4; e += stride) {
        int4 s = src4[e];
        int4 d = dst4[e];
        __hip_atomic_fetch_add(&base[d.x], pack_val(x[s.x]),
                               __ATOMIC_RELAXED, __HIP_MEMORY_SCOPE_WORKGROUP);
        __hip_atomic_fetch_add(&base[d.y], pack_val(x[s.y]),
                               __ATOMIC_RELAXED, __HIP_MEMORY_SCOPE_WORKGROUP);
        __hip_atomic_fetch_add(&base[d.z], pack_val(x[s.z]),
                               __ATOMIC_RELAXED, __HIP_MEMORY_SCOPE_WORKGROUP);
        __hip_atomic_fetch_add(&base[d.w], pack_val(x[s.w]),
                               __ATOMIC_RELAXED, __HIP_MEMORY_SCOPE_WORKGROUP);
    }
    int t = (E4 << 2) + i;
    if (t < E) {
        __hip_atomic_fetch_add(&base[ei[E + t]], pack_val(x[ei[t]]),
                               __ATOMIC_RELAXED, __HIP_MEMORY_SCOPE_WORKGROUP);
    }
}

// ---------------------------------------------------------------------------
// Edge pass 2: s28[xcc][dst] += p[src]   (f32, L2-local atomic)
__global__ void edge_pass2_kernel(const int* __restrict__ ei,
                                  const float* __restrict__ p,
                                  float* __restrict__ s28,
                                  int E, int N) {
    float* __restrict__ base = s28 + (size_t)get_xcc_id() * (size_t)N;
    const int4* src4 = (const int4*)ei;
    const int4* dst4 = (const int4*)(ei + E);
    int E4 = E >> 2;
    int i = blockIdx.x * blockDim.x + threadIdx.x;
    int stride = gridDim.x * blockDim.x;
    for (int e = i; e < E4; e += stride) {
        int4 s = src4[e];
        int4 d = dst4[e];
        __hip_atomic_fetch_add(&base[d.x], p[s.x],
                               __ATOMIC_RELAXED, __HIP_MEMORY_SCOPE_WORKGROUP);
        __hip_atomic_fetch_add(&base[d.y], p[s.y],
                               __ATOMIC_RELAXED, __HIP_MEMORY_SCOPE_WORKGROUP);
        __hip_atomic_fetch_add(&base[d.z], p[s.z],
                               __ATOMIC_RELAXED, __HIP_MEMORY_SCOPE_WORKGROUP);
        __hip_atomic_fetch_add(&base[d.w], p[s.w],
                               __ATOMIC_RELAXED, __HIP_MEMORY_SCOPE_WORKGROUP);
    }
    int t = (E4 << 2) + i;
    if (t < E) {
        __hip_atomic_fetch_add(&base[ei[E + t]], p[ei[t]],
                               __ATOMIC_RELAXED, __HIP_MEMORY_SCOPE_WORKGROUP);
    }
}

// ---------------------------------------------------------------------------
// Node pass 1: reduce 8 packed copies -> (sum1, deg); compute
// h[f] = relu(mean1*W1l[f] + b1[f] + x*W1r[f]); p = h.W2l, q = h.W2r.
__global__ void node_pass1_kernel(const float* __restrict__ x,
                                  const unsigned long long* __restrict__ pack8,
                                  const float* __restrict__ W1l,
                                  const float* __restrict__ b1,
                                  const float* __restrict__ W1r,
                                  const float* __restrict__ W2l,
                                  const float* __restrict__ W2r,
                                  float* __restrict__ deg_out,
                                  float* __restrict__ p,
                                  float* __restrict__ q,
                                  int N) {
    __shared__ float s_w1l[16], s_b1[16], s_w1r[16], s_w2l[16], s_w2r[16];
    if (threadIdx.x < 16) {
        s_w1l[threadIdx.x] = W1l[threadIdx.x];
        s_b1[threadIdx.x]  = b1[threadIdx.x];
        s_w1r[threadIdx.x] = W1r[threadIdx.x];
        s_w2l[threadIdx.x] = W2l[threadIdx.x];
        s_w2r[threadIdx.x] = W2r[threadIdx.x];
    }
    __syncthreads();
    int n = blockIdx.x * blockDim.x + threadIdx.x;
    if (n >= N) return;

    unsigned long long tot = 0;
#pragma unroll
    for (int k = 0; k < NUM_XCD; ++k) tot += pack8[(size_t)k * N + n];
    unsigned degi = (unsigned)(tot >> 42);
    double low = (double)(tot & ((1ULL << 42) - 1));
    float sum = (float)((low - (double)degi * 2147483648.0) * (1.0 / 1048576.0));
    float dg = (float)degi;
    float m = sum / fmaxf(dg, 1.0f);

    float xv = x[n];
    float pa = 0.0f, qa = 0.0f;
#pragma unroll
    for (int f = 0; f < 16; ++f) {
        float h = fmaf(m, s_w1l[f], fmaf(xv, s_w1r[f], s_b1[f]));
        h = fmaxf(h, 0.0f);
        pa = fmaf(h, s_w2l[f], pa);
        qa = fmaf(h, s_w2r[f], qa);
    }
    deg_out[n] = dg;
    p[n] = pa;
    q[n] = qa;
}

// ---------------------------------------------------------------------------
// Node pass 2 + pool: s2 = sum_k s28[k][n]; h2 = s2/max(deg,1) + b2 + q;
// out[batch[n]] += h2 (batch sorted -> wave-segmented reduction).
__global__ void node_pass2_kernel(const float* __restrict__ s28,
                                  const float* __restrict__ deg,
                                  const float* __restrict__ q,
                                  const float* __restrict__ b2,
                                  const int* __restrict__ batch,
                                  float* __restrict__ out,
                                  int N) {
    int i = blockIdx.x * blockDim.x + threadIdx.x;
    float b2v = b2[0];
    float val = 0.0f;
    int g;
    if (i < N) {
        float s2 = 0.0f;
#pragma unroll
        for (int k = 0; k < NUM_XCD; ++k) s2 += s28[(size_t)k * N + i];
        val = s2 / fmaxf(deg[i], 1.0f) + b2v + q[i];
        g = batch[i];
    } else {
        g = batch[N - 1];  // pad lanes contribute 0 to a valid graph id
    }
    int g0 = __shfl(g, 0);
    unsigned long long same = __ballot(g == g0);
    if (same == ~0ULL) {
        for (int off = 32; off > 0; off >>= 1) val += __shfl_down(val, off);
        if ((threadIdx.x & 63) == 0) atomicAdd(&out[g0], val);
    } else {
        atomicAdd(&out[g], val);
    }
}

// ---------------------------------------------------------------------------
extern "C" void kernel_launch(void* const* d_in, const int* in_sizes, int n_in,
                              void* d_out, int out_size, void* d_ws, size_t ws_size,
                              hipStream_t stream) {
    const float* x     = (const float*)d_in[0];
    const int*   ei    = (const int*)d_in[1];   // [2, E] flat: src then dst
    const int*   batch = (const int*)d_in[2];
    // d_in[3] = batch_size scalar (== out_size), unused
    const float* W1l = (const float*)d_in[4];
    const float* b1  = (const float*)d_in[5];
    const float* W1r = (const float*)d_in[6];
    const float* W2l = (const float*)d_in[7];
    const float* b2  = (const float*)d_in[8];
    const float* W2r = (const float*)d_in[9];

    const int N = in_sizes[0];        // 200000
    const int E = in_sizes[1] / 2;    // 6400000
    float* out = (float*)d_out;       // [512]

    // workspace layout (float units):
    //   [0, 16N)   : pack8 (u64[8][N]) for pass 1; ALIASED as s28 (f32[8][N])
    //                for pass 2 (re-zeroed in between)
    //   [16N, 17N) : deg
    //   [17N, 18N) : p
    //   [18N, 19N) : q
    unsigned long long* pack8 = (unsigned long long*)d_ws;
    float* s28 = (float*)d_ws;
    float* deg = (float*)d_ws + (size_t)16 * N;
    float* p   = deg + N;
    float* q   = p + N;

    hipMemsetAsync(d_out, 0, (size_t)out_size * sizeof(float), stream);
    hipMemsetAsync(pack8, 0, (size_t)NUM_XCD * N * sizeof(unsigned long long), stream);

    const int BS = 256;
    int E4 = E >> 2;
    int edge_blocks = (E4 + BS - 1) / BS;
    int node_blocks = (N + BS - 1) / BS;

    edge_pass1_kernel<<<edge_blocks, BS, 0, stream>>>(ei, x, pack8, E, N);
    node_pass1_kernel<<<node_blocks, BS, 0, stream>>>(x, pack8, W1l, b1, W1r,
                                                      W2l, W2r, deg, p, q, N);
    hipMemsetAsync(s28, 0, (size_t)NUM_XCD * N * sizeof(float), stream);
    edge_pass2_kernel<<<edge_blocks, BS, 0, stream>>>(ei, p, s28, E, N);
    node_pass2_kernel<<<node_blocks, BS, 0, stream>>>(s28, deg, q, b2, batch,
                                                      out, N);
}

// Round 3
// 267.827 us; speedup vs baseline: 3.9598x; 2.6916x over previous
//
#include <hip/hip_runtime.h>

// GNN_Critic: 2-layer SAGEConv (F: 1 -> 16 -> 1) + global_add_pool.
// p[n] = h[n,:].W2l (edge-aggregated -> s2), q[n] = h[n,:].W2r; the 16-dim
// hidden vector is never materialized.
//
// Round-3 structural change: measured evidence shows global atomics execute
// memory-side at ~1 atomic/cycle/XCD (~20.5 G/s device) with 32 B EA traffic
// each, regardless of scope. So the edge scatter-reduction is done entirely
// with LDS atomics: nodes partitioned into P parts of 40000 bins (160 KB LDS,
// fixed-point i32), edges into C chunks; block (p,c) scans chunk c, bins
// dst-in-part-p hits in LDS, flushes bins with plain stores to slab[c];
// a node pass reduces the C slab entries per node. Zero global atomics on
// the edge path.

#define BINS     40000        // bins per node-part; LDS = 160000 B
#define BLK      1024
#define CNT_ONE  (1u << 25)   // pass-1 count field: bits [31:25]
#define FX_BIAS  131072       // 2^17 per-add bias keeps sum field positive
#define SCALE    4096.0f      // 2^12 fixed-point scale
#define INV_SCALE (1.0f / 4096.0f)

// ---------------------------------------------------------------------------
// Pass-1 edge binning: bins[dst] += pack(count=1, x[src])
__global__ __launch_bounds__(BLK) void
edge_bin1_kernel(const int* __restrict__ ei, const float* __restrict__ x,
                 unsigned* __restrict__ slab, int E, int N, int P, int Epc) {
    extern __shared__ unsigned bins[];
    int c  = blockIdx.x / P;
    int p  = blockIdx.x - c * P;
    int lo = p * BINS;
    int nb = min(N - lo, BINS);
    for (int j = threadIdx.x; j < nb; j += BLK) bins[j] = 0;
    __syncthreads();

    int e0 = c * Epc;
    int e1 = min(E, e0 + Epc);
    const int4* s4 = (const int4*)ei;
    const int4* d4 = (const int4*)(ei + E);
    int q0 = e0 >> 2;
    int q1 = ((E & 3) == 0) ? (e1 >> 2) : q0;   // vector path only if aligned
    for (int e = q0 + (int)threadIdx.x; e < q1; e += BLK) {
        int4 d = d4[e];
        int4 s = s4[e];
        unsigned r;
        r = (unsigned)(d.x - lo);
        if (r < (unsigned)nb)
            atomicAdd(&bins[r], CNT_ONE + (unsigned)((int)rintf(x[s.x] * SCALE) + FX_BIAS));
        r = (unsigned)(d.y - lo);
        if (r < (unsigned)nb)
            atomicAdd(&bins[r], CNT_ONE + (unsigned)((int)rintf(x[s.y] * SCALE) + FX_BIAS));
        r = (unsigned)(d.z - lo);
        if (r < (unsigned)nb)
            atomicAdd(&bins[r], CNT_ONE + (unsigned)((int)rintf(x[s.z] * SCALE) + FX_BIAS));
        r = (unsigned)(d.w - lo);
        if (r < (unsigned)nb)
            atomicAdd(&bins[r], CNT_ONE + (unsigned)((int)rintf(x[s.w] * SCALE) + FX_BIAS));
    }
    int t0 = max(e0, q1 << 2);   // scalar tail
    for (int e = t0 + (int)threadIdx.x; e < e1; e += BLK) {
        unsigned r = (unsigned)(ei[E + e] - lo);
        if (r < (unsigned)nb)
            atomicAdd(&bins[r], CNT_ONE + (unsigned)((int)rintf(x[ei[e]] * SCALE) + FX_BIAS));
    }
    __syncthreads();
    unsigned* dst = slab + (size_t)c * N + lo;
    for (int j = threadIdx.x; j < nb; j += BLK) dst[j] = bins[j];
}

// ---------------------------------------------------------------------------
// Pass-2 edge binning: bins[dst] += fix(p[src])   (signed i32)
__global__ __launch_bounds__(BLK) void
edge_bin2_kernel(const int* __restrict__ ei, const float* __restrict__ pv,
                 int* __restrict__ slab, int E, int N, int P, int Epc) {
    extern __shared__ int binsI[];
    int c  = blockIdx.x / P;
    int p  = blockIdx.x - c * P;
    int lo = p * BINS;
    int nb = min(N - lo, BINS);
    for (int j = threadIdx.x; j < nb; j += BLK) binsI[j] = 0;
    __syncthreads();

    int e0 = c * Epc;
    int e1 = min(E, e0 + Epc);
    const int4* s4 = (const int4*)ei;
    const int4* d4 = (const int4*)(ei + E);
    int q0 = e0 >> 2;
    int q1 = ((E & 3) == 0) ? (e1 >> 2) : q0;
    for (int e = q0 + (int)threadIdx.x; e < q1; e += BLK) {
        int4 d = d4[e];
        int4 s = s4[e];
        unsigned r;
        r = (unsigned)(d.x - lo);
        if (r < (unsigned)nb) atomicAdd(&binsI[r], (int)rintf(pv[s.x] * SCALE));
        r = (unsigned)(d.y - lo);
        if (r < (unsigned)nb) atomicAdd(&binsI[r], (int)rintf(pv[s.y] * SCALE));
        r = (unsigned)(d.z - lo);
        if (r < (unsigned)nb) atomicAdd(&binsI[r], (int)rintf(pv[s.z] * SCALE));
        r = (unsigned)(d.w - lo);
        if (r < (unsigned)nb) atomicAdd(&binsI[r], (int)rintf(pv[s.w] * SCALE));
    }
    int t0 = max(e0, q1 << 2);
    for (int e = t0 + (int)threadIdx.x; e < e1; e += BLK) {
        unsigned r = (unsigned)(ei[E + e] - lo);
        if (r < (unsigned)nb) atomicAdd(&binsI[r], (int)rintf(pv[ei[e]] * SCALE));
    }
    __syncthreads();
    int* dst = slab + (size_t)c * N + lo;
    for (int j = threadIdx.x; j < nb; j += BLK) dst[j] = binsI[j];
}

// ---------------------------------------------------------------------------
// Node pass 1: reduce C slab entries -> (sum1, deg); compute
// h[f] = relu(mean1*W1l[f] + b1[f] + x*W1r[f]); p = h.W2l, q = h.W2r.
__global__ void node_pass1_kernel(const float* __restrict__ x,
                                  const unsigned* __restrict__ slab,
                                  const float* __restrict__ W1l,
                                  const float* __restrict__ b1,
                                  const float* __restrict__ W1r,
                                  const float* __restrict__ W2l,
                                  const float* __restrict__ W2r,
                                  float* __restrict__ deg_out,
                                  float* __restrict__ p,
                                  float* __restrict__ q,
                                  int N, int C) {
    __shared__ float s_w1l[16], s_b1[16], s_w1r[16], s_w2l[16], s_w2r[16];
    if (threadIdx.x < 16) {
        s_w1l[threadIdx.x] = W1l[threadIdx.x];
        s_b1[threadIdx.x]  = b1[threadIdx.x];
        s_w1r[threadIdx.x] = W1r[threadIdx.x];
        s_w2l[threadIdx.x] = W2l[threadIdx.x];
        s_w2r[threadIdx.x] = W2r[threadIdx.x];
    }
    __syncthreads();
    int n = blockIdx.x * blockDim.x + threadIdx.x;
    if (n >= N) return;

    unsigned cnt = 0, fx = 0;
    for (int c = 0; c < C; ++c) {
        unsigned w = slab[(size_t)c * N + n];
        cnt += w >> 25;
        fx  += w & (CNT_ONE - 1);
    }
    float dg  = (float)cnt;
    float sum = (float)(int)(fx - cnt * (unsigned)FX_BIAS) * INV_SCALE;
    float m   = sum / fmaxf(dg, 1.0f);

    float xv = x[n];
    float pa = 0.0f, qa = 0.0f;
#pragma unroll
    for (int f = 0; f < 16; ++f) {
        float h = fmaf(m, s_w1l[f], fmaf(xv, s_w1r[f], s_b1[f]));
        h = fmaxf(h, 0.0f);
        pa = fmaf(h, s_w2l[f], pa);
        qa = fmaf(h, s_w2r[f], qa);
    }
    deg_out[n] = dg;
    p[n] = pa;
    q[n] = qa;
}

// ---------------------------------------------------------------------------
// Node pass 2 + pool: s2 = sum_c slab2[c][n]; h2 = s2/max(deg,1) + b2 + q;
// out[batch[n]] += h2 (batch sorted -> wave-segmented reduction).
__global__ void node_pass2_kernel(const int* __restrict__ slab2,
                                  const float* __restrict__ deg,
                                  const float* __restrict__ q,
                                  const float* __restrict__ b2,
                                  const int* __restrict__ batch,
                                  float* __restrict__ out,
                                  int N, int C) {
    int i = blockIdx.x * blockDim.x + threadIdx.x;
    float b2v = b2[0];
    float val = 0.0f;
    int g;
    if (i < N) {
        int sacc = 0;
        for (int c = 0; c < C; ++c) sacc += slab2[(size_t)c * N + i];
        float s2 = (float)sacc * INV_SCALE;
        val = s2 / fmaxf(deg[i], 1.0f) + b2v + q[i];
        g = batch[i];
    } else {
        g = batch[N - 1];  // pad lanes contribute 0 to a valid graph id
    }
    int g0 = __shfl(g, 0);
    unsigned long long same = __ballot(g == g0);
    if (same == ~0ULL) {
        for (int off = 32; off > 0; off >>= 1) val += __shfl_down(val, off);
        if ((threadIdx.x & 63) == 0) atomicAdd(&out[g0], val);
    } else {
        atomicAdd(&out[g], val);
    }
}

// ---------------------------------------------------------------------------
extern "C" void kernel_launch(void* const* d_in, const int* in_sizes, int n_in,
                              void* d_out, int out_size, void* d_ws, size_t ws_size,
                              hipStream_t stream) {
    const float* x     = (const float*)d_in[0];
    const int*   ei    = (const int*)d_in[1];   // [2, E] flat: src then dst
    const int*   batch = (const int*)d_in[2];
    const float* W1l = (const float*)d_in[4];
    const float* b1  = (const float*)d_in[5];
    const float* W1r = (const float*)d_in[6];
    const float* W2l = (const float*)d_in[7];
    const float* b2  = (const float*)d_in[8];
    const float* W2r = (const float*)d_in[9];

    const int N = in_sizes[0];        // 200000
    const int E = in_sizes[1] / 2;    // 6400000
    float* out = (float*)d_out;       // [512]

    const int P = (N + BINS - 1) / BINS;   // 5 node-parts

    // Adaptive chunk count: slab = C*N words, plus deg/p/q = 3N floats.
    long long wsWords = (long long)(ws_size / 4);
    long long cAvail  = (wsWords - 3LL * N) / N;
    int C = (int)(cAvail < 1 ? 1 : (cAvail > 51 ? 51 : cAvail));
    int Epc = (((E + C - 1) / C) + 3) & ~3;       // chunk size, multiple of 4

    // workspace layout (4-byte words): slab[C][N] | deg[N] | p[N] | q[N]
    unsigned* slab1 = (unsigned*)d_ws;
    int*      slab2 = (int*)d_ws;                  // reused after node_pass1
    float* deg = (float*)d_ws + (size_t)C * N;
    float* p   = deg + N;
    float* q   = p + N;

    hipMemsetAsync(d_out, 0, (size_t)out_size * sizeof(float), stream);

    const int shmem = BINS * 4;                    // 160000 B dynamic LDS
    hipFuncSetAttribute((const void*)edge_bin1_kernel,
                        hipFuncAttributeMaxDynamicSharedMemorySize, shmem);
    hipFuncSetAttribute((const void*)edge_bin2_kernel,
                        hipFuncAttributeMaxDynamicSharedMemorySize, shmem);

    const int NB = 256;
    int node_blocks = (N + NB - 1) / NB;

    edge_bin1_kernel<<<P * C, BLK, shmem, stream>>>(ei, x, slab1, E, N, P, Epc);
    node_pass1_kernel<<<node_blocks, NB, 0, stream>>>(x, slab1, W1l, b1, W1r,
                                                      W2l, W2r, deg, p, q, N, C);
    edge_bin2_kernel<<<P * C, BLK, shmem, stream>>>(ei, p, slab2, E, N, P, Epc);
    node_pass2_kernel<<<node_blocks, NB, 0, stream>>>(slab2, deg, q, b2, batch,
                                                      out, N, C);
}

// Round 4
// 220.627 us; speedup vs baseline: 4.8069x; 1.2139x over previous
//
#include <hip/hip_runtime.h>

// GNN_Critic: 2-layer SAGEConv (F: 1 -> 16 -> 1) + global_add_pool.
// p[n] = h[n,:].W2l (edge-aggregated -> s2), q[n] = h[n,:].W2r; the 16-dim
// hidden vector is never materialized.
//
// Round-4: counting-partition the edges by dst ONCE into P=16 buckets of
// packed u32 (src:18 | localDst:14), via LDS-staged coalesced flushes
// (~25K global atomics total). Both bin passes then read only their own
// part's edges exactly once (round-3 re-read the full edge list P=5x per
// pass). Binning stays in LDS (12500 bins/part, fixed-point), flushed to a
// C=16 slab, reduced in the node passes. Zero global atomics on hot paths.

#define PP        16            // node parts / buckets
#define BLK       1024
#define SCAP      1024u         // per-part LDS staging ring capacity (u32)
#define SMASK     1023u
#define TILE      (BLK * 4)     // 4096 edges per partition block
#define CBIN      16            // slab chunks per part
#define CNT_ONE   (1u << 25)    // pass-1 count field bits [31:25]
#define FX_BIAS   131072        // 2^17 per-add bias keeps sum field positive
#define SCALE     4096.0f       // 2^12 fixed-point scale
#define INV_SCALE (1.0f / 4096.0f)

// ---------------------------------------------------------------------------
// Counting partition: one tile of 4096 edges per block. Stage packed words in
// per-part LDS rings, drain coalesced with one tail-atomic per part.
__global__ __launch_bounds__(BLK) void partition_kernel(
    const int* __restrict__ ei, unsigned* __restrict__ pairs,
    unsigned* __restrict__ tails, int E, int bins, unsigned Mdiv, int cap) {
    extern __shared__ unsigned buf[];                 // [PP][SCAP] = 64 KB
    __shared__ unsigned cnt[PP], base[PP], fq[PP], gb[PP];
    const int tid = threadIdx.x;
    if (tid < PP) { cnt[tid] = 0; base[tid] = 0; }
    __syncthreads();

    int b0 = blockIdx.x * TILE;
    int e0 = b0 + tid * 4;
    int nv = E - e0; nv = nv < 0 ? 0 : (nv > 4 ? 4 : nv);
    int srcv[4], dstv[4];
    if (nv == 4 && ((E & 3) == 0)) {
        int4 s = *(const int4*)(ei + e0);
        int4 d = *(const int4*)(ei + E + e0);
        srcv[0] = s.x; srcv[1] = s.y; srcv[2] = s.z; srcv[3] = s.w;
        dstv[0] = d.x; dstv[1] = d.y; dstv[2] = d.z; dstv[3] = d.w;
    } else {
        for (int j = 0; j < nv; ++j) { srcv[j] = ei[e0 + j]; dstv[j] = ei[E + e0 + j]; }
    }
    unsigned w[4]; int part[4]; bool pend[4];
    for (int j = 0; j < 4; ++j) {
        pend[j] = (j < nv);
        if (pend[j]) {
            unsigned dst = (unsigned)dstv[j];
            unsigned pt = (unsigned)(((unsigned long long)dst * Mdiv) >> 32);
            int ld = (int)dst - (int)pt * bins;
            while (ld >= bins) { ld -= bins; ++pt; }
            while (ld < 0)     { ld += bins; --pt; }
            part[j] = (int)pt;
            w[j] = ((unsigned)srcv[j] << 14) | (unsigned)ld;
        }
    }
    // insertion (overflow cannot occur for random input; retry loop is the
    // correctness guarantee for pathological part skew)
    for (int j = 0; j < 4; ++j) {
        if (pend[j]) {
            unsigned slot = atomicAdd(&cnt[part[j]], 1u);
            if (slot - base[part[j]] < SCAP) {
                buf[part[j] * SCAP + (slot & SMASK)] = w[j]; pend[j] = false;
            } else atomicSub(&cnt[part[j]], 1u);
        }
    }
    int npend = __syncthreads_count((int)(pend[0] | pend[1] | pend[2] | pend[3]));
    while (npend > 0) {
        if (tid < PP) {
            unsigned avail = cnt[tid] - base[tid];
            unsigned f = avail & ~511u;
            fq[tid] = f;
            if (f) gb[tid] = atomicAdd(&tails[tid], f);
        }
        __syncthreads();
        {
            int wv = tid >> 6, lane = tid & 63;
            unsigned f = fq[wv];
            if (f) {
                unsigned g0 = gb[wv], bs = base[wv];
                unsigned mx = (g0 + f <= (unsigned)cap) ? f : ((unsigned)cap > g0 ? (unsigned)cap - g0 : 0u);
                unsigned* dp = pairs + (size_t)wv * cap + g0;
                for (unsigned jj = lane; jj < mx; jj += 64)
                    dp[jj] = buf[wv * SCAP + ((bs + jj) & SMASK)];
            }
        }
        __syncthreads();
        if (tid < PP) base[tid] += fq[tid];
        __syncthreads();
        for (int j = 0; j < 4; ++j) {
            if (pend[j]) {
                unsigned slot = atomicAdd(&cnt[part[j]], 1u);
                if (slot - base[part[j]] < SCAP) {
                    buf[part[j] * SCAP + (slot & SMASK)] = w[j]; pend[j] = false;
                } else atomicSub(&cnt[part[j]], 1u);
            }
        }
        npend = __syncthreads_count((int)(pend[0] | pend[1] | pend[2] | pend[3]));
    }
    // final drain
    if (tid < PP) {
        unsigned avail = cnt[tid] - base[tid];
        fq[tid] = avail;
        if (avail) gb[tid] = atomicAdd(&tails[tid], avail);
    }
    __syncthreads();
    {
        int wv = tid >> 6, lane = tid & 63;
        unsigned f = fq[wv];
        if (f) {
            unsigned g0 = gb[wv], bs = base[wv];
            unsigned mx = (g0 + f <= (unsigned)cap) ? f : ((unsigned)cap > g0 ? (unsigned)cap - g0 : 0u);
            unsigned* dp = pairs + (size_t)wv * cap + g0;
            for (unsigned jj = lane; jj < mx; jj += 64)
                dp[jj] = buf[wv * SCAP + ((bs + jj) & SMASK)];
        }
    }
}

// ---------------------------------------------------------------------------
// Bin pass 1: bins[ld] += pack(count=1, x[src]) over this (part, chunk).
__global__ __launch_bounds__(BLK) void bin1_kernel(
    const unsigned* __restrict__ pairs, const unsigned* __restrict__ tails,
    const float* __restrict__ x, unsigned* __restrict__ slab,
    int N, int bins, int cap) {
    extern __shared__ unsigned sb[];
    int p = blockIdx.x & (PP - 1);
    int c = blockIdx.x / PP;
    int len = (int)tails[p]; if (len > cap) len = cap;
    int st = (int)((long long)len * c / CBIN);
    int en = (int)((long long)len * (c + 1) / CBIN);
    for (int j = threadIdx.x; j < bins; j += BLK) sb[j] = 0;
    __syncthreads();
    const unsigned* bp = pairs + (size_t)p * cap;
    int st4 = (st + 3) & ~3;
    int en4 = en & ~3;
    int preEnd = st4 < en ? st4 : en;
    for (int e = st + (int)threadIdx.x; e < preEnd; e += BLK) {
        unsigned wv = bp[e];
        atomicAdd(&sb[wv & 16383u],
                  CNT_ONE + (unsigned)((int)rintf(x[wv >> 14] * SCALE) + FX_BIAS));
    }
    if (st4 < en4) {
        const uint4* bp4 = (const uint4*)(bp + st4);
        int n4 = (en4 - st4) >> 2;
        for (int e = threadIdx.x; e < n4; e += BLK) {
            uint4 wq = bp4[e];
            atomicAdd(&sb[wq.x & 16383u],
                      CNT_ONE + (unsigned)((int)rintf(x[wq.x >> 14] * SCALE) + FX_BIAS));
            atomicAdd(&sb[wq.y & 16383u],
                      CNT_ONE + (unsigned)((int)rintf(x[wq.y >> 14] * SCALE) + FX_BIAS));
            atomicAdd(&sb[wq.z & 16383u],
                      CNT_ONE + (unsigned)((int)rintf(x[wq.z >> 14] * SCALE) + FX_BIAS));
            atomicAdd(&sb[wq.w & 16383u],
                      CNT_ONE + (unsigned)((int)rintf(x[wq.w >> 14] * SCALE) + FX_BIAS));
        }
    }
    int tailSt = st4 > en4 ? st4 : en4;
    for (int e = tailSt + (int)threadIdx.x; e < en; e += BLK) {
        unsigned wv = bp[e];
        atomicAdd(&sb[wv & 16383u],
                  CNT_ONE + (unsigned)((int)rintf(x[wv >> 14] * SCALE) + FX_BIAS));
    }
    __syncthreads();
    unsigned* dst = slab + (size_t)c * N + (size_t)p * bins;
    int nb = N - p * bins; if (nb > bins) nb = bins;
    for (int j = threadIdx.x; j < nb; j += BLK) dst[j] = sb[j];
}

// ---------------------------------------------------------------------------
// Bin pass 2: bins[ld] += fix(p[src])  (signed i32)
__global__ __launch_bounds__(BLK) void bin2_kernel(
    const unsigned* __restrict__ pairs, const unsigned* __restrict__ tails,
    const float* __restrict__ pv, int* __restrict__ slab,
    int N, int bins, int cap) {
    extern __shared__ int sbi[];
    int p = blockIdx.x & (PP - 1);
    int c = blockIdx.x / PP;
    int len = (int)tails[p]; if (len > cap) len = cap;
    int st = (int)((long long)len * c / CBIN);
    int en = (int)((long long)len * (c + 1) / CBIN);
    for (int j = threadIdx.x; j < bins; j += BLK) sbi[j] = 0;
    __syncthreads();
    const unsigned* bp = pairs + (size_t)p * cap;
    int st4 = (st + 3) & ~3;
    int en4 = en & ~3;
    int preEnd = st4 < en ? st4 : en;
    for (int e = st + (int)threadIdx.x; e < preEnd; e += BLK) {
        unsigned wv = bp[e];
        atomicAdd(&sbi[wv & 16383u], (int)rintf(pv[wv >> 14] * SCALE));
    }
    if (st4 < en4) {
        const uint4* bp4 = (const uint4*)(bp + st4);
        int n4 = (en4 - st4) >> 2;
        for (int e = threadIdx.x; e < n4; e += BLK) {
            uint4 wq = bp4[e];
            atomicAdd(&sbi[wq.x & 16383u], (int)rintf(pv[wq.x >> 14] * SCALE));
            atomicAdd(&sbi[wq.y & 16383u], (int)rintf(pv[wq.y >> 14] * SCALE));
            atomicAdd(&sbi[wq.z & 16383u], (int)rintf(pv[wq.z >> 14] * SCALE));
            atomicAdd(&sbi[wq.w & 16383u], (int)rintf(pv[wq.w >> 14] * SCALE));
        }
    }
    int tailSt = st4 > en4 ? st4 : en4;
    for (int e = tailSt + (int)threadIdx.x; e < en; e += BLK) {
        unsigned wv = bp[e];
        atomicAdd(&sbi[wv & 16383u], (int)rintf(pv[wv >> 14] * SCALE));
    }
    __syncthreads();
    int* dst = slab + (size_t)c * N + (size_t)p * bins;
    int nb = N - p * bins; if (nb > bins) nb = bins;
    for (int j = threadIdx.x; j < nb; j += BLK) dst[j] = sbi[j];
}

// ---------------------------------------------------------------------------
// Node pass 1: reduce CBIN slab entries -> (sum1, deg); compute
// h[f] = relu(mean1*W1l[f] + b1[f] + x*W1r[f]); p = h.W2l, q = h.W2r.
__global__ void node_pass1_kernel(const float* __restrict__ x,
                                  const unsigned* __restrict__ slab,
                                  const float* __restrict__ W1l,
                                  const float* __restrict__ b1,
                                  const float* __restrict__ W1r,
                                  const float* __restrict__ W2l,
                                  const float* __restrict__ W2r,
                                  float* __restrict__ deg_out,
                                  float* __restrict__ pv,
                                  float* __restrict__ qv,
                                  int N) {
    __shared__ float s_w1l[16], s_b1[16], s_w1r[16], s_w2l[16], s_w2r[16];
    if (threadIdx.x < 16) {
        s_w1l[threadIdx.x] = W1l[threadIdx.x];
        s_b1[threadIdx.x]  = b1[threadIdx.x];
        s_w1r[threadIdx.x] = W1r[threadIdx.x];
        s_w2l[threadIdx.x] = W2l[threadIdx.x];
        s_w2r[threadIdx.x] = W2r[threadIdx.x];
    }
    __syncthreads();
    int n = blockIdx.x * blockDim.x + threadIdx.x;
    if (n >= N) return;

    unsigned cnt = 0, fx = 0;
#pragma unroll
    for (int c = 0; c < CBIN; ++c) {
        unsigned w = slab[(size_t)c * N + n];
        cnt += w >> 25;
        fx  += w & (CNT_ONE - 1);
    }
    float dg  = (float)cnt;
    float sum = (float)(int)(fx - cnt * (unsigned)FX_BIAS) * INV_SCALE;
    float m   = sum / fmaxf(dg, 1.0f);

    float xv = x[n];
    float pa = 0.0f, qa = 0.0f;
#pragma unroll
    for (int f = 0; f < 16; ++f) {
        float h = fmaf(m, s_w1l[f], fmaf(xv, s_w1r[f], s_b1[f]));
        h = fmaxf(h, 0.0f);
        pa = fmaf(h, s_w2l[f], pa);
        qa = fmaf(h, s_w2r[f], qa);
    }
    deg_out[n] = dg;
    pv[n] = pa;
    qv[n] = qa;
}

// ---------------------------------------------------------------------------
// Node pass 2 + pool: s2 = sum_c slab2[c][n]; h2 = s2/max(deg,1) + b2 + q;
// out[batch[n]] += h2 (batch sorted -> wave-segmented reduction).
__global__ void node_pass2_kernel(const int* __restrict__ slab2,
                                  const float* __restrict__ deg,
                                  const float* __restrict__ qv,
                                  const float* __restrict__ b2,
                                  const int* __restrict__ batch,
                                  float* __restrict__ out,
                                  int N) {
    int i = blockIdx.x * blockDim.x + threadIdx.x;
    float b2v = b2[0];
    float val = 0.0f;
    int g;
    if (i < N) {
        int sacc = 0;
#pragma unroll
        for (int c = 0; c < CBIN; ++c) sacc += slab2[(size_t)c * N + i];
        float s2 = (float)sacc * INV_SCALE;
        val = s2 / fmaxf(deg[i], 1.0f) + b2v + qv[i];
        g = batch[i];
    } else {
        g = batch[N - 1];  // pad lanes contribute 0 to a valid graph id
    }
    int g0 = __shfl(g, 0);
    unsigned long long same = __ballot(g == g0);
    if (same == ~0ULL) {
        for (int off = 32; off > 0; off >>= 1) val += __shfl_down(val, off);
        if ((threadIdx.x & 63) == 0) atomicAdd(&out[g0], val);
    } else {
        atomicAdd(&out[g], val);
    }
}

// ---------------------------------------------------------------------------
extern "C" void kernel_launch(void* const* d_in, const int* in_sizes, int n_in,
                              void* d_out, int out_size, void* d_ws, size_t ws_size,
                              hipStream_t stream) {
    const float* x     = (const float*)d_in[0];
    const int*   ei    = (const int*)d_in[1];   // [2, E] flat: src then dst
    const int*   batch = (const int*)d_in[2];
    const float* W1l = (const float*)d_in[4];
    const float* b1  = (const float*)d_in[5];
    const float* W1r = (const float*)d_in[6];
    const float* W2l = (const float*)d_in[7];
    const float* b2  = (const float*)d_in[8];
    const float* W2r = (const float*)d_in[9];

    const int N = in_sizes[0];        // 200000
    const int E = in_sizes[1] / 2;    // 6400000
    float* out = (float*)d_out;       // [512]

    const int bins = (N + PP - 1) / PP;                       // 12500
    const unsigned Mdiv =
        (unsigned)(((1ULL << 32) + (unsigned)bins - 1) / (unsigned)bins);
    const int EperP = E / PP;
    int cap = ((EperP + EperP / 32 + 4096) + 1023) & ~1023;   // ~20-sigma margin

    // workspace (u32 words): pairs[PP][cap] | slab[CBIN][N] | deg|p|q (f32) | tails[PP]
    unsigned* pairs = (unsigned*)d_ws;
    unsigned* slab1 = pairs + (size_t)PP * cap;
    int*      slab2 = (int*)slab1;
    float* deg = (float*)(slab1 + (size_t)CBIN * N);
    float* pv  = deg + N;
    float* qv  = pv + N;
    unsigned* tails = (unsigned*)(qv + N);

    hipMemsetAsync(d_out, 0, (size_t)out_size * sizeof(float), stream);
    hipMemsetAsync(tails, 0, PP * sizeof(unsigned), stream);

    const int partShmem = PP * (int)SCAP * 4;   // 65536 B
    const int binShmem  = bins * 4;             // 50000 B
    hipFuncSetAttribute((const void*)partition_kernel,
                        hipFuncAttributeMaxDynamicSharedMemorySize, partShmem);
    hipFuncSetAttribute((const void*)bin1_kernel,
                        hipFuncAttributeMaxDynamicSharedMemorySize, binShmem);
    hipFuncSetAttribute((const void*)bin2_kernel,
                        hipFuncAttributeMaxDynamicSharedMemorySize, binShmem);

    int partBlocks = (E + TILE - 1) / TILE;     // 1563
    const int NB = 256;
    int node_blocks = (N + NB - 1) / NB;

    partition_kernel<<<partBlocks, BLK, partShmem, stream>>>(ei, pairs, tails,
                                                             E, bins, Mdiv, cap);
    bin1_kernel<<<PP * CBIN, BLK, binShmem, stream>>>(pairs, tails, x, slab1,
                                                      N, bins, cap);
    node_pass1_kernel<<<node_blocks, NB, 0, stream>>>(x, slab1, W1l, b1, W1r,
                                                      W2l, W2r, deg, pv, qv, N);
    bin2_kernel<<<PP * CBIN, BLK, binShmem, stream>>>(pairs, tails, pv, slab2,
                                                      N, bins, cap);
    node_pass2_kernel<<<node_blocks, NB, 0, stream>>>(slab2, deg, qv, b2, batch,
                                                      out, N);
}